// Round 2
// baseline (3556.672 us; speedup 1.0000x reference)
//
#include <hip/hip_runtime.h>

typedef __bf16 bf16_t;
typedef __bf16 bf16x8 __attribute__((ext_vector_type(8)));
typedef float f32x4 __attribute__((ext_vector_type(4)));

#define NB 16
#define NS 512
#define ND 768
#define NH 12
#define NFF 3072
#define NL 6
#define NHD 64
#define NM (NB*NS)   // 8192 token rows

static __device__ __forceinline__ f32x4 mfma16(bf16x8 a, bf16x8 b, f32x4 c) {
    return __builtin_amdgcn_mfma_f32_16x16x32_bf16(a, b, c, 0, 0, 0);
}

// dtype-dual load: isbf ? bf16[i] : f32[i]
static __device__ __forceinline__ float loadf(const void* p, size_t i, int isbf) {
    return isbf ? (float)((const bf16_t*)p)[i] : ((const float*)p)[i];
}

// -------------------- dtype detection (emb_ln_s is all-ones) --------------------
__global__ void detect_dtype(const void* elns, int* flag) {
    if (threadIdx.x == 0 && blockIdx.x == 0) {
        unsigned u = *(const unsigned*)elns;
        *flag = (u != 0x3F800000u) ? 1 : 0;   // f32 1.0f bit pattern -> f32 inputs
    }
}

// -------------------- weight transpose: src [K,N] (f32 or bf16) -> dst bf16 [N,K] ----
__global__ __launch_bounds__(256) void transpose_bt(const void* __restrict__ src, size_t eoff,
                                                    bf16_t* __restrict__ dst, int K, int N,
                                                    const int* __restrict__ flagp) {
    const int isbf = flagp[0];
    __shared__ bf16_t t[32][33];
    int nn0 = blockIdx.x * 32, kk0 = blockIdx.y * 32;
    int tx = threadIdx.x, ty = threadIdx.y;  // 32 x 8
    #pragma unroll
    for (int i = 0; i < 4; i++)
        t[ty + i*8][tx] = (bf16_t)loadf(src, eoff + (size_t)(kk0 + ty + i*8) * N + nn0 + tx, isbf);
    __syncthreads();
    #pragma unroll
    for (int i = 0; i < 4; i++)
        dst[(size_t)(nn0 + ty + i*8) * K + kk0 + tx] = t[tx][ty + i*8];
}

// -------------------- block reduce (sum,sumsq) over 256 threads --------------------
static __device__ __forceinline__ void blockReduce2(float& a, float& b, float* redbuf, int tid) {
    #pragma unroll
    for (int o = 32; o; o >>= 1) { a += __shfl_xor(a, o); b += __shfl_xor(b, o); }
    int wv = tid >> 6;
    if ((tid & 63) == 0) { redbuf[wv] = a; redbuf[4 + wv] = b; }
    __syncthreads();
    a = redbuf[0] + redbuf[1] + redbuf[2] + redbuf[3];
    b = redbuf[4] + redbuf[5] + redbuf[6] + redbuf[7];
    __syncthreads();
}

// -------------------- embedding segment-sum merge + pos emb + LN --------------------
__global__ __launch_bounds__(256) void embed_ln(const int* __restrict__ ids,
                                                const int* __restrict__ segs,
                                                const void* __restrict__ emb,
                                                const void* __restrict__ pos,
                                                const void* __restrict__ gamma,
                                                const void* __restrict__ beta,
                                                float* __restrict__ x, bf16_t* __restrict__ xb,
                                                const int* __restrict__ flagp) {
    const int isbf = flagp[0];
    int b = blockIdx.y, sq = blockIdx.x, tid = threadIdx.x;
    __shared__ int slo, shi;
    __shared__ float redbuf[8];
    if (tid == 0) { slo = 1 << 30; shi = -1; }
    __syncthreads();
    const int* segrow = segs + b * NS;
    const int* idrow  = ids  + b * NS;
    for (int p = tid; p < NS; p += 256)
        if (segrow[p] == sq) { atomicMin(&slo, p); atomicMax(&shi, p); }
    __syncthreads();
    int lo = slo, hi = shi;
    float vals[3];
    #pragma unroll
    for (int i = 0; i < 3; i++) {
        int d = tid + i * 256;
        float s;
        if (hi >= lo) {
            s = 0.f;
            for (int p = lo; p <= hi; p++) s += loadf(emb, (size_t)idrow[p] * ND + d, isbf);
        } else {
            s = loadf(emb, d, isbf);  // pad: emb row of token id 0
        }
        vals[i] = s + loadf(pos, (size_t)sq * ND + d, isbf);
    }
    float sum = vals[0] + vals[1] + vals[2];
    float sq2 = vals[0]*vals[0] + vals[1]*vals[1] + vals[2]*vals[2];
    blockReduce2(sum, sq2, redbuf, tid);
    float mean = sum / ND;
    float var  = sq2 / ND - mean * mean;
    float rs = rsqrtf(fmaxf(var, 0.f) + 1e-12f);
    size_t rowoff = ((size_t)b * NS + sq) * ND;
    #pragma unroll
    for (int i = 0; i < 3; i++) {
        int d = tid + i * 256;
        float o = (vals[i] - mean) * rs * loadf(gamma, d, isbf) + loadf(beta, d, isbf);
        x[rowoff + d] = o;
        xb[rowoff + d] = (bf16_t)o;
    }
}

// -------------------- row LayerNorm in-place on f32 x, also emits bf16 xb ----------
__global__ __launch_bounds__(256) void ln_rows(float* __restrict__ x,
                                               const void* __restrict__ gamma, size_t goff,
                                               const void* __restrict__ beta, size_t boff,
                                               bf16_t* __restrict__ xb,
                                               const int* __restrict__ flagp) {
    const int isbf = flagp[0];
    int row = blockIdx.x, tid = threadIdx.x;
    __shared__ float redbuf[8];
    size_t rowoff = (size_t)row * ND;
    float vals[3];
    #pragma unroll
    for (int i = 0; i < 3; i++) vals[i] = x[rowoff + tid + i * 256];
    float sum = vals[0] + vals[1] + vals[2];
    float sq2 = vals[0]*vals[0] + vals[1]*vals[1] + vals[2]*vals[2];
    blockReduce2(sum, sq2, redbuf, tid);
    float mean = sum / ND;
    float var  = sq2 / ND - mean * mean;
    float rs = rsqrtf(fmaxf(var, 0.f) + 1e-12f);
    #pragma unroll
    for (int i = 0; i < 3; i++) {
        int d = tid + i * 256;
        float o = (vals[i] - mean) * rs * loadf(gamma, goff + d, isbf) + loadf(beta, boff + d, isbf);
        x[rowoff + d] = o;
        xb[rowoff + d] = (bf16_t)o;
    }
}

// -------------------- MFMA GEMM: C[M,N] = A[M,K] * Bt[N,K]^T + bias --------------------
// mode 0: write bf16 scattered to [B,H,S,HD] (QKV)
// mode 1: f32 out[idx] += C + bias        (in-place residual accumulate)
// mode 2: write bf16 gelu(C + bias)       (FF1)
__global__ __launch_bounds__(256) void gemm_bt(const bf16_t* __restrict__ A,
                                               const bf16_t* __restrict__ Bt,
                                               const void* __restrict__ bias, size_t boff,
                                               void* __restrict__ out,
                                               int N_, int K_, int mode,
                                               const int* __restrict__ flagp) {
    const int isbf = flagp[0];
    __shared__ __align__(16) bf16_t As[128][72];
    __shared__ __align__(16) bf16_t Bs[128][72];
    int tid = threadIdx.x, wave = tid >> 6, lane = tid & 63;
    int lm = lane & 15, quad = lane >> 4;
    int m0 = blockIdx.y * 128, n0 = blockIdx.x * 128;
    int wm = (wave >> 1) * 64, wn = (wave & 1) * 64;
    f32x4 acc[4][4] = {};
    const bf16_t* Arow = A + (size_t)m0 * K_;
    const bf16_t* Brow = Bt + (size_t)n0 * K_;
    int ra = tid >> 3, ca = (tid & 7) * 8;
    for (int k0 = 0; k0 < K_; k0 += 64) {
        __syncthreads();
        #pragma unroll
        for (int i = 0; i < 4; i++) {
            int r = ra + i * 32;
            *(bf16x8*)(&As[r][ca]) = *(const bf16x8*)(Arow + (size_t)r * K_ + k0 + ca);
            *(bf16x8*)(&Bs[r][ca]) = *(const bf16x8*)(Brow + (size_t)r * K_ + k0 + ca);
        }
        __syncthreads();
        #pragma unroll
        for (int ks = 0; ks < 64; ks += 32) {
            bf16x8 af[4], bfv[4];
            #pragma unroll
            for (int t = 0; t < 4; t++) {
                af[t]  = *(const bf16x8*)(&As[wm + t*16 + lm][ks + quad*8]);
                bfv[t] = *(const bf16x8*)(&Bs[wn + t*16 + lm][ks + quad*8]);
            }
            #pragma unroll
            for (int mt = 0; mt < 4; mt++)
                #pragma unroll
                for (int nt = 0; nt < 4; nt++)
                    acc[mt][nt] = mfma16(af[mt], bfv[nt], acc[mt][nt]);
        }
    }
    #pragma unroll
    for (int mt = 0; mt < 4; mt++)
    #pragma unroll
    for (int nt = 0; nt < 4; nt++)
    #pragma unroll
    for (int r = 0; r < 4; r++) {
        int mrow = m0 + wm + mt*16 + quad*4 + r;
        int ncol = n0 + wn + nt*16 + lm;
        float val = acc[mt][nt][r] + loadf(bias, boff + ncol, isbf);
        if (mode == 0) {
            int bb = mrow >> 9, sp = mrow & 511, hh = ncol >> 6, hd = ncol & 63;
            ((bf16_t*)out)[(((size_t)(bb*NH + hh) * NS) + sp) * NHD + hd] = (bf16_t)val;
        } else if (mode == 1) {
            size_t idx = (size_t)mrow * N_ + ncol;
            ((float*)out)[idx] += val;
        } else {
            size_t idx = (size_t)mrow * N_ + ncol;
            float g = 0.5f * val * (1.0f + erff(val * 0.70710678118654752f));
            ((bf16_t*)out)[idx] = (bf16_t)g;
        }
    }
}

// -------------------- fused attention: per (b,h,32 q rows), LDS < 64KB --------------
__global__ __launch_bounds__(256) void attn(const bf16_t* __restrict__ q,
                                            const bf16_t* __restrict__ k,
                                            const bf16_t* __restrict__ v,
                                            const int* __restrict__ mask,
                                            bf16_t* __restrict__ ctx) {
    __shared__ __align__(16) bf16_t sc[32][520];
    __shared__ __align__(16) bf16_t kv[64][72];
    __shared__ float rinv[32];
    int tid = threadIdx.x, w = tid >> 6, lane = tid & 63;
    int lm = lane & 15, quad = lane >> 4;
    int mtw = w >> 1, nhw = w & 1;
    int b = blockIdx.z, h = blockIdx.y, q0 = blockIdx.x * 32;
    const bf16_t* Qg = q + (((size_t)(b*NH + h) * NS) + q0) * NHD;
    const bf16_t* Kg = k + ((size_t)(b*NH + h) * NS) * NHD;
    const bf16_t* Vg = v + ((size_t)(b*NH + h) * NS) * NHD;
    bf16x8 aq0 = *(const bf16x8*)(Qg + (mtw*16 + lm) * NHD + quad*8);
    bf16x8 aq1 = *(const bf16x8*)(Qg + (mtw*16 + lm) * NHD + 32 + quad*8);
    int sr = tid >> 2, scol = (tid & 3) * 16;
    // phase A: scores = Q K^T / 8 + mask bias
    for (int kc = 0; kc < NS; kc += 64) {
        __syncthreads();
        *(bf16x8*)(&kv[sr][scol])     = *(const bf16x8*)(Kg + (size_t)(kc + sr) * NHD + scol);
        *(bf16x8*)(&kv[sr][scol + 8]) = *(const bf16x8*)(Kg + (size_t)(kc + sr) * NHD + scol + 8);
        __syncthreads();
        #pragma unroll
        for (int nt = 0; nt < 2; nt++) {
            int ncl = nhw*32 + nt*16 + lm;
            bf16x8 b0 = *(const bf16x8*)(&kv[ncl][quad*8]);
            bf16x8 b1 = *(const bf16x8*)(&kv[ncl][32 + quad*8]);
            f32x4 a = {};
            a = mfma16(aq0, b0, a);
            a = mfma16(aq1, b1, a);
            int col = kc + ncl;
            float mb = (mask[b*NS + col] == 0) ? -1e9f : 0.0f;
            #pragma unroll
            for (int r = 0; r < 4; r++)
                sc[mtw*16 + quad*4 + r][col] = (bf16_t)(a[r] * 0.125f + mb);
        }
    }
    __syncthreads();
    // phase B: softmax per row (wave handles 8 rows); store unnormalized exp
    for (int r = 0; r < 8; r++) {
        int row = w*8 + r;
        float mx = -3.0e38f;
        #pragma unroll
        for (int i = 0; i < 8; i++) mx = fmaxf(mx, (float)sc[row][lane + i*64]);
        #pragma unroll
        for (int o = 32; o; o >>= 1) mx = fmaxf(mx, __shfl_xor(mx, o));
        float sum = 0.f;
        #pragma unroll
        for (int i = 0; i < 8; i++) {
            float p = __expf((float)sc[row][lane + i*64] - mx);
            sc[row][lane + i*64] = (bf16_t)p;
            sum += p;
        }
        #pragma unroll
        for (int o = 32; o; o >>= 1) sum += __shfl_xor(sum, o);
        if (lane == 0) rinv[row] = 1.0f / sum;
    }
    // phase C: ctx = P V (V staged transposed), scale by 1/sum at the end
    f32x4 oc[2] = {};
    for (int kc = 0; kc < NS; kc += 64) {
        __syncthreads();
        {
            bf16x8 v0 = *(const bf16x8*)(Vg + (size_t)(kc + sr) * NHD + scol);
            bf16x8 v1 = *(const bf16x8*)(Vg + (size_t)(kc + sr) * NHD + scol + 8);
            #pragma unroll
            for (int j = 0; j < 8; j++) { kv[scol + j][sr] = v0[j]; kv[scol + 8 + j][sr] = v1[j]; }
        }
        __syncthreads();
        #pragma unroll
        for (int ks = 0; ks < 2; ks++) {
            bf16x8 ap = *(const bf16x8*)(&sc[mtw*16 + lm][kc + ks*32 + quad*8]);
            #pragma unroll
            for (int nt = 0; nt < 2; nt++) {
                int d = nhw*32 + nt*16 + lm;
                bf16x8 bv = *(const bf16x8*)(&kv[d][ks*32 + quad*8]);
                oc[nt] = mfma16(ap, bv, oc[nt]);
            }
        }
    }
    #pragma unroll
    for (int nt = 0; nt < 2; nt++)
    #pragma unroll
    for (int r = 0; r < 4; r++) {
        int row = mtw*16 + quad*4 + r;
        float val = oc[nt][r] * rinv[row];
        ctx[((size_t)(b*NS) + q0 + row) * ND + h*NHD + nhw*32 + nt*16 + lm] = (bf16_t)val;
    }
}

// -------------------- classifier head --------------------
__global__ __launch_bounds__(256) void head(const float* __restrict__ x,
                                            const void* __restrict__ preW,
                                            const void* __restrict__ preb,
                                            const void* __restrict__ clsW,
                                            const void* __restrict__ clsb,
                                            void* __restrict__ out,
                                            const int* __restrict__ flagp) {
    const int isbf = flagp[0];
    int b = blockIdx.x, tid = threadIdx.x;
    __shared__ float xr[ND];
    __shared__ float pr[ND];
    __shared__ float red[256];
    for (int d = tid; d < ND; d += 256) xr[d] = x[((size_t)b * NS) * ND + d];
    __syncthreads();
    for (int n = tid; n < ND; n += 256) {
        float s = loadf(preb, n, isbf);
        for (int kk = 0; kk < ND; kk++) s += xr[kk] * loadf(preW, (size_t)kk * ND + n, isbf);
        pr[n] = fmaxf(s, 0.f);
    }
    __syncthreads();
    for (int c = 0; c < 3; c++) {
        float s = 0.f;
        for (int kk = tid; kk < ND; kk += 256) s += pr[kk] * loadf(clsW, kk * 3 + c, isbf);
        red[tid] = s;
        __syncthreads();
        for (int off = 128; off; off >>= 1) {
            if (tid < off) red[tid] += red[tid + off];
            __syncthreads();
        }
        if (tid == 0) {
            float v = red[0] + loadf(clsb, c, isbf);
            if (isbf) ((bf16_t*)out)[b * 3 + c] = (bf16_t)v;
            else      ((float*)out)[b * 3 + c] = v;
        }
        __syncthreads();
    }
}

// -------------------- workspace layout (~102.3 MB) --------------------
static const size_t SZ_ACT_BF = (size_t)NM * ND * 2;        // 12,582,912
static const size_t SZ_ACT_F  = (size_t)NM * ND * 4;        // 25,165,824
static const size_t SZ_WSQ    = (size_t)ND * ND * 2;        // 1,179,648  (one layer [N,K])
static const size_t SZ_WF     = (size_t)ND * NFF * 2;       // 4,718,592
static const size_t OFF_QB   = 0;
static const size_t OFF_KB   = OFF_QB + SZ_ACT_BF;
static const size_t OFF_VB   = OFF_KB + SZ_ACT_BF;
static const size_t OFF_CTX  = OFF_VB + SZ_ACT_BF;          // h1b aliases [OFF_QB, OFF_X)
static const size_t OFF_X    = OFF_CTX + SZ_ACT_BF;
static const size_t OFF_XB   = OFF_X + SZ_ACT_F;
static const size_t OFF_WQ   = OFF_XB + SZ_ACT_BF;
static const size_t OFF_WK   = OFF_WQ + SZ_WSQ;
static const size_t OFF_WV   = OFF_WK + SZ_WSQ;
static const size_t OFF_WO   = OFF_WV + SZ_WSQ;
static const size_t OFF_W1   = OFF_WO + SZ_WSQ;
static const size_t OFF_W2   = OFF_W1 + SZ_WF;
static const size_t OFF_FLAG = OFF_W2 + SZ_WF;

extern "C" void kernel_launch(void* const* d_in, const int* in_sizes, int n_in,
                              void* d_out, int out_size, void* d_ws, size_t ws_size,
                              hipStream_t stream) {
    const int* ids   = (const int*)d_in[0];
    const int* segs  = (const int*)d_in[1];
    const int* mask  = (const int*)d_in[2];
    const void* emb  = d_in[4];
    const void* pos  = d_in[5];
    const void* elns = d_in[6];
    const void* elnb = d_in[7];
    const void* Wq = d_in[8];  const void* bq = d_in[9];
    const void* Wk = d_in[10]; const void* bk = d_in[11];
    const void* Wv = d_in[12]; const void* bv = d_in[13];
    const void* Wo = d_in[14]; const void* bo = d_in[15];
    const void* l1s = d_in[16]; const void* l1b = d_in[17];
    const void* W1 = d_in[18];  const void* b1 = d_in[19];
    const void* W2 = d_in[20];  const void* b2 = d_in[21];
    const void* l2s = d_in[22]; const void* l2b = d_in[23];
    const void* preW = d_in[24]; const void* preb = d_in[25];
    const void* clsW = d_in[26]; const void* clsb = d_in[27];

    char* ws = (char*)d_ws;
    bf16_t* qb   = (bf16_t*)(ws + OFF_QB);
    bf16_t* kb   = (bf16_t*)(ws + OFF_KB);
    bf16_t* vb   = (bf16_t*)(ws + OFF_VB);
    bf16_t* ctxb = (bf16_t*)(ws + OFF_CTX);
    bf16_t* h1b  = (bf16_t*)(ws + OFF_QB);   // aliases q/k/v/ctx (dead by FF1)
    float*  x    = (float*)(ws + OFF_X);
    bf16_t* xb   = (bf16_t*)(ws + OFF_XB);
    bf16_t* wq_t = (bf16_t*)(ws + OFF_WQ);
    bf16_t* wk_t = (bf16_t*)(ws + OFF_WK);
    bf16_t* wv_t = (bf16_t*)(ws + OFF_WV);
    bf16_t* wo_t = (bf16_t*)(ws + OFF_WO);
    bf16_t* w1_t = (bf16_t*)(ws + OFF_W1);
    bf16_t* w2_t = (bf16_t*)(ws + OFF_W2);
    int*    flag = (int*)(ws + OFF_FLAG);

    detect_dtype<<<1, 64, 0, stream>>>(elns, flag);
    embed_ln<<<dim3(NS, NB), 256, 0, stream>>>(ids, segs, emb, pos, elns, elnb, x, xb, flag);

    dim3 tb(32, 8);
    for (int l = 0; l < NL; l++) {
        size_t oq = (size_t)l * ND * ND, of = (size_t)l * ND * NFF;
        transpose_bt<<<dim3(24, 24), tb, 0, stream>>>(Wq, oq, wq_t, ND, ND, flag);
        transpose_bt<<<dim3(24, 24), tb, 0, stream>>>(Wk, oq, wk_t, ND, ND, flag);
        transpose_bt<<<dim3(24, 24), tb, 0, stream>>>(Wv, oq, wv_t, ND, ND, flag);
        transpose_bt<<<dim3(24, 24), tb, 0, stream>>>(Wo, oq, wo_t, ND, ND, flag);
        transpose_bt<<<dim3(96, 24), tb, 0, stream>>>(W1, of, w1_t, ND, NFF, flag);
        transpose_bt<<<dim3(24, 96), tb, 0, stream>>>(W2, of, w2_t, NFF, ND, flag);

        gemm_bt<<<dim3(6, 64), 256, 0, stream>>>(xb, wq_t, bq, (size_t)l*ND, qb, ND, ND, 0, flag);
        gemm_bt<<<dim3(6, 64), 256, 0, stream>>>(xb, wk_t, bk, (size_t)l*ND, kb, ND, ND, 0, flag);
        gemm_bt<<<dim3(6, 64), 256, 0, stream>>>(xb, wv_t, bv, (size_t)l*ND, vb, ND, ND, 0, flag);
        attn<<<dim3(16, NH, NB), 256, 0, stream>>>(qb, kb, vb, mask, ctxb);
        gemm_bt<<<dim3(6, 64), 256, 0, stream>>>(ctxb, wo_t, bo, (size_t)l*ND, x, ND, ND, 1, flag);
        ln_rows<<<NM, 256, 0, stream>>>(x, l1s, (size_t)l*ND, l1b, (size_t)l*ND, xb, flag);
        gemm_bt<<<dim3(24, 64), 256, 0, stream>>>(xb, w1_t, b1, (size_t)l*NFF, h1b, NFF, ND, 2, flag);
        gemm_bt<<<dim3(6, 64), 256, 0, stream>>>(h1b, w2_t, b2, (size_t)l*ND, x, ND, NFF, 1, flag);
        ln_rows<<<NM, 256, 0, stream>>>(x, l2s, (size_t)l*ND, l2b, (size_t)l*ND, xb, flag);
    }

    head<<<NB, 256, 0, stream>>>(x, preW, preb, clsW, clsb, d_out, flag);
}

// Round 3
// 3008.844 us; speedup vs baseline: 1.1821x; 1.1821x over previous
//
#include <hip/hip_runtime.h>

typedef __bf16 bf16_t;
typedef __bf16 bf16x8 __attribute__((ext_vector_type(8)));
typedef float f32x4 __attribute__((ext_vector_type(4)));

#define NB 16
#define NS 512
#define ND 768
#define NH 12
#define NFF 3072
#define NL 6
#define NHD 64
#define NM (NB*NS)   // 8192 token rows
static const size_t NQKV = (size_t)NB * NH * NS * NHD;   // 6,291,456 elems per Q/K/V buffer

static __device__ __forceinline__ f32x4 mfma16(bf16x8 a, bf16x8 b, f32x4 c) {
    return __builtin_amdgcn_mfma_f32_16x16x32_bf16(a, b, c, 0, 0, 0);
}

// dtype-dual load: isbf ? bf16[i] : f32[i]
static __device__ __forceinline__ float loadf(const void* p, size_t i, int isbf) {
    return isbf ? (float)((const bf16_t*)p)[i] : ((const float*)p)[i];
}

// async global->LDS, 16B per lane; LDS dest = wave-uniform base + lane*16
static __device__ __forceinline__ void gload_lds16(const bf16_t* g, bf16_t* l) {
    __builtin_amdgcn_global_load_lds((const __attribute__((address_space(1))) void*)g,
                                     (__attribute__((address_space(3))) void*)l, 16, 0, 0);
}

// -------------------- dtype detection (emb_ln_s is all-ones) --------------------
__global__ void detect_dtype(const void* elns, int* flag) {
    if (threadIdx.x == 0 && blockIdx.x == 0) {
        unsigned u = *(const unsigned*)elns;
        *flag = (u != 0x3F800000u) ? 1 : 0;
    }
}

// -------------------- weight transpose: src [K,N] (f32/bf16) -> dst bf16 [N,K] ------
__global__ __launch_bounds__(256) void transpose_bt(const void* __restrict__ src, size_t src_off,
                                                    size_t src_lstride,
                                                    bf16_t* __restrict__ dst, size_t dst_lstride,
                                                    int K, int N, const int* __restrict__ flagp) {
    const int isbf = flagp[0];
    __shared__ bf16_t t[32][33];
    int l = blockIdx.z;
    size_t so = src_off + (size_t)l * src_lstride;
    bf16_t* d = dst + (size_t)l * dst_lstride;
    int nn0 = blockIdx.x * 32, kk0 = blockIdx.y * 32;
    int tx = threadIdx.x, ty = threadIdx.y;  // 32 x 8
    #pragma unroll
    for (int i = 0; i < 4; i++)
        t[ty + i*8][tx] = (bf16_t)loadf(src, so + (size_t)(kk0 + ty + i*8) * N + nn0 + tx, isbf);
    __syncthreads();
    #pragma unroll
    for (int i = 0; i < 4; i++)
        d[(size_t)(nn0 + ty + i*8) * K + kk0 + tx] = t[tx][ty + i*8];
}

// -------------------- block reduce (sum,sumsq) over 256 threads --------------------
static __device__ __forceinline__ void blockReduce2(float& a, float& b, float* redbuf, int tid) {
    #pragma unroll
    for (int o = 32; o; o >>= 1) { a += __shfl_xor(a, o); b += __shfl_xor(b, o); }
    int wv = tid >> 6;
    if ((tid & 63) == 0) { redbuf[wv] = a; redbuf[4 + wv] = b; }
    __syncthreads();
    a = redbuf[0] + redbuf[1] + redbuf[2] + redbuf[3];
    b = redbuf[4] + redbuf[5] + redbuf[6] + redbuf[7];
    __syncthreads();
}

// -------------------- embedding segment-sum merge + pos emb + LN --------------------
__global__ __launch_bounds__(256) void embed_ln(const int* __restrict__ ids,
                                                const int* __restrict__ segs,
                                                const void* __restrict__ emb,
                                                const void* __restrict__ pos,
                                                const void* __restrict__ gamma,
                                                const void* __restrict__ beta,
                                                float* __restrict__ x, bf16_t* __restrict__ xb,
                                                const int* __restrict__ flagp) {
    const int isbf = flagp[0];
    int b = blockIdx.y, sq = blockIdx.x, tid = threadIdx.x;
    __shared__ int slo, shi;
    __shared__ float redbuf[8];
    if (tid == 0) { slo = 1 << 30; shi = -1; }
    __syncthreads();
    const int* segrow = segs + b * NS;
    const int* idrow  = ids  + b * NS;
    for (int p = tid; p < NS; p += 256)
        if (segrow[p] == sq) { atomicMin(&slo, p); atomicMax(&shi, p); }
    __syncthreads();
    int lo = slo, hi = shi;
    float vals[3];
    #pragma unroll
    for (int i = 0; i < 3; i++) {
        int d = tid + i * 256;
        float s;
        if (hi >= lo) {
            s = 0.f;
            for (int p = lo; p <= hi; p++) s += loadf(emb, (size_t)idrow[p] * ND + d, isbf);
        } else {
            s = loadf(emb, d, isbf);
        }
        vals[i] = s + loadf(pos, (size_t)sq * ND + d, isbf);
    }
    float sum = vals[0] + vals[1] + vals[2];
    float sq2 = vals[0]*vals[0] + vals[1]*vals[1] + vals[2]*vals[2];
    blockReduce2(sum, sq2, redbuf, tid);
    float mean = sum / ND;
    float var  = sq2 / ND - mean * mean;
    float rs = rsqrtf(fmaxf(var, 0.f) + 1e-12f);
    size_t rowoff = ((size_t)b * NS + sq) * ND;
    #pragma unroll
    for (int i = 0; i < 3; i++) {
        int d = tid + i * 256;
        float o = (vals[i] - mean) * rs * loadf(gamma, d, isbf) + loadf(beta, d, isbf);
        x[rowoff + d] = o;
        xb[rowoff + d] = (bf16_t)o;
    }
}

// -------------------- row LayerNorm in-place on f32 x, also emits bf16 xb ----------
__global__ __launch_bounds__(256) void ln_rows(float* __restrict__ x,
                                               const void* __restrict__ gamma, size_t goff,
                                               const void* __restrict__ beta, size_t boff,
                                               bf16_t* __restrict__ xb,
                                               const int* __restrict__ flagp) {
    const int isbf = flagp[0];
    int row = blockIdx.x, tid = threadIdx.x;
    __shared__ float redbuf[8];
    size_t rowoff = (size_t)row * ND;
    float vals[3];
    #pragma unroll
    for (int i = 0; i < 3; i++) vals[i] = x[rowoff + tid + i * 256];
    float sum = vals[0] + vals[1] + vals[2];
    float sq2 = vals[0]*vals[0] + vals[1]*vals[1] + vals[2]*vals[2];
    blockReduce2(sum, sq2, redbuf, tid);
    float mean = sum / ND;
    float var  = sq2 / ND - mean * mean;
    float rs = rsqrtf(fmaxf(var, 0.f) + 1e-12f);
    #pragma unroll
    for (int i = 0; i < 3; i++) {
        int d = tid + i * 256;
        float o = (vals[i] - mean) * rs * loadf(gamma, goff + d, isbf) + loadf(beta, boff + d, isbf);
        x[rowoff + d] = o;
        xb[rowoff + d] = (bf16_t)o;
    }
}

// -------------------- MFMA GEMM: C[M,N] = A[M,K] * Bt[N,K]^T + bias --------------------
// LDS: unpadded [128][64], 16B-chunk XOR swizzle (chunk_stored = chunk ^ (row&7)),
// staged via global_load_lds dwordx4 (lane-contiguous DMA).
// mode 0: fused QKV scatter -> q/k/v [B,H,S,HD] bf16 (N_=2304, bias0/1/2)
// mode 1: f32 out[idx] += C + bias0      (in-place residual accumulate)
// mode 2: bf16 out = gelu(C + bias0)     (FF1)
__global__ __launch_bounds__(256) void gemm_bt(const bf16_t* __restrict__ A,
                                               const bf16_t* __restrict__ Bt,
                                               const void* __restrict__ bias0,
                                               const void* __restrict__ bias1,
                                               const void* __restrict__ bias2,
                                               size_t boff, void* __restrict__ out,
                                               int N_, int K_, int mode,
                                               const int* __restrict__ flagp) {
    const int isbf = flagp[0];
    __shared__ __align__(16) bf16_t As[128 * 64];
    __shared__ __align__(16) bf16_t Bs[128 * 64];
    int tid = threadIdx.x, wave = tid >> 6, lane = tid & 63;
    int lm = lane & 15, quad = lane >> 4;
    int m0 = blockIdx.y * 128, n0 = blockIdx.x * 128;
    int wm = (wave >> 1) * 64, wn = (wave & 1) * 64;
    f32x4 acc[4][4] = {};
    const bf16_t* Ag = A + (size_t)m0 * K_;
    const bf16_t* Bg = Bt + (size_t)n0 * K_;
    int lr = lane >> 3, lc = lane & 7;
    for (int k0 = 0; k0 < K_; k0 += 64) {
        __syncthreads();
        #pragma unroll
        for (int j = 0; j < 4; j++) {
            int sg = wave * 4 + j;            // 16 segments of 8 rows
            int r  = sg * 8 + lr;
            int c  = lc ^ (r & 7);            // fetch the chunk that belongs at slot lc
            gload_lds16(Ag + (size_t)r * K_ + k0 + c * 8, As + sg * 512);
            gload_lds16(Bg + (size_t)r * K_ + k0 + c * 8, Bs + sg * 512);
        }
        __syncthreads();
        #pragma unroll
        for (int ks = 0; ks < 2; ks++) {
            bf16x8 af[4], bfv[4];
            #pragma unroll
            for (int t = 0; t < 4; t++) {
                int ra = wm + t*16 + lm;
                af[t]  = *(const bf16x8*)(As + ra*64 + (((ks*4 + quad) ^ (ra & 7)) << 3));
                int rb = wn + t*16 + lm;
                bfv[t] = *(const bf16x8*)(Bs + rb*64 + (((ks*4 + quad) ^ (rb & 7)) << 3));
            }
            #pragma unroll
            for (int mt = 0; mt < 4; mt++)
                #pragma unroll
                for (int nt = 0; nt < 4; nt++)
                    acc[mt][nt] = mfma16(af[mt], bfv[nt], acc[mt][nt]);
        }
    }
    #pragma unroll
    for (int mt = 0; mt < 4; mt++)
    #pragma unroll
    for (int nt = 0; nt < 4; nt++)
    #pragma unroll
    for (int r = 0; r < 4; r++) {
        int mrow = m0 + wm + mt*16 + quad*4 + r;
        int ncol = n0 + wn + nt*16 + lm;
        if (mode == 0) {
            int which = ncol / 768;
            int col = ncol - which * 768;
            const void* bsel = which == 0 ? bias0 : (which == 1 ? bias1 : bias2);
            float val = acc[mt][nt][r] + loadf(bsel, boff + col, isbf);
            int bbx = mrow >> 9, sp = mrow & 511, hh = col >> 6, hd = col & 63;
            ((bf16_t*)out)[(size_t)which * NQKV + (((size_t)(bbx*NH + hh) * NS) + sp) * NHD + hd] = (bf16_t)val;
        } else if (mode == 1) {
            float val = acc[mt][nt][r] + loadf(bias0, boff + ncol, isbf);
            size_t idx = (size_t)mrow * N_ + ncol;
            ((float*)out)[idx] += val;
        } else {
            float val = acc[mt][nt][r] + loadf(bias0, boff + ncol, isbf);
            size_t idx = (size_t)mrow * N_ + ncol;
            float g = 0.5f * val * (1.0f + erff(val * 0.70710678118654752f));
            ((bf16_t*)out)[idx] = (bf16_t)g;
        }
    }
}

// -------------------- fused attention: per (b,h,32 q rows) --------------
__global__ __launch_bounds__(256) void attn(const bf16_t* __restrict__ q,
                                            const bf16_t* __restrict__ k,
                                            const bf16_t* __restrict__ v,
                                            const int* __restrict__ mask,
                                            bf16_t* __restrict__ ctx) {
    __shared__ __align__(16) bf16_t sc[32][520];
    __shared__ __align__(16) bf16_t kv[64][72];
    __shared__ float rinv[32];
    int tid = threadIdx.x, w = tid >> 6, lane = tid & 63;
    int lm = lane & 15, quad = lane >> 4;
    int mtw = w >> 1, nhw = w & 1;
    int b = blockIdx.z, h = blockIdx.y, q0 = blockIdx.x * 32;
    const bf16_t* Qg = q + (((size_t)(b*NH + h) * NS) + q0) * NHD;
    const bf16_t* Kg = k + ((size_t)(b*NH + h) * NS) * NHD;
    const bf16_t* Vg = v + ((size_t)(b*NH + h) * NS) * NHD;
    bf16x8 aq0 = *(const bf16x8*)(Qg + (mtw*16 + lm) * NHD + quad*8);
    bf16x8 aq1 = *(const bf16x8*)(Qg + (mtw*16 + lm) * NHD + 32 + quad*8);
    int sr = tid >> 2, scol = (tid & 3) * 16;
    // phase A: scores = Q K^T / 8 + mask bias
    for (int kc = 0; kc < NS; kc += 64) {
        __syncthreads();
        *(bf16x8*)(&kv[sr][scol])     = *(const bf16x8*)(Kg + (size_t)(kc + sr) * NHD + scol);
        *(bf16x8*)(&kv[sr][scol + 8]) = *(const bf16x8*)(Kg + (size_t)(kc + sr) * NHD + scol + 8);
        __syncthreads();
        #pragma unroll
        for (int nt = 0; nt < 2; nt++) {
            int ncl = nhw*32 + nt*16 + lm;
            bf16x8 b0 = *(const bf16x8*)(&kv[ncl][quad*8]);
            bf16x8 b1 = *(const bf16x8*)(&kv[ncl][32 + quad*8]);
            f32x4 a = {};
            a = mfma16(aq0, b0, a);
            a = mfma16(aq1, b1, a);
            int col = kc + ncl;
            float mb = (mask[b*NS + col] == 0) ? -1e9f : 0.0f;
            #pragma unroll
            for (int r = 0; r < 4; r++)
                sc[mtw*16 + quad*4 + r][col] = (bf16_t)(a[r] * 0.125f + mb);
        }
    }
    __syncthreads();
    // phase B: softmax, all 32 rows in parallel (row = tid/8, 8 lanes per row)
    {
        int row = tid >> 3, part = tid & 7;
        bf16_t* base = &sc[row][part * 64];
        bf16x8 pv[8];
        float mx = -3.0e38f;
        #pragma unroll
        for (int i = 0; i < 8; i++) {
            pv[i] = *(const bf16x8*)(base + i * 8);
            #pragma unroll
            for (int j = 0; j < 8; j++) mx = fmaxf(mx, (float)pv[i][j]);
        }
        mx = fmaxf(mx, __shfl_xor(mx, 1));
        mx = fmaxf(mx, __shfl_xor(mx, 2));
        mx = fmaxf(mx, __shfl_xor(mx, 4));
        float sum = 0.f;
        #pragma unroll
        for (int i = 0; i < 8; i++) {
            bf16x8 pe;
            #pragma unroll
            for (int j = 0; j < 8; j++) {
                float p = __expf((float)pv[i][j] - mx);
                pe[j] = (bf16_t)p;
                sum += p;
            }
            *(bf16x8*)(base + i * 8) = pe;
        }
        sum += __shfl_xor(sum, 1);
        sum += __shfl_xor(sum, 2);
        sum += __shfl_xor(sum, 4);
        if (part == 0) rinv[row] = 1.0f / sum;
    }
    // phase C: ctx = P V (V staged transposed), scale by 1/sum at the end
    f32x4 oc[2] = {};
    for (int kc = 0; kc < NS; kc += 64) {
        __syncthreads();
        {
            bf16x8 v0 = *(const bf16x8*)(Vg + (size_t)(kc + sr) * NHD + scol);
            bf16x8 v1 = *(const bf16x8*)(Vg + (size_t)(kc + sr) * NHD + scol + 8);
            #pragma unroll
            for (int j = 0; j < 8; j++) { kv[scol + j][sr] = v0[j]; kv[scol + 8 + j][sr] = v1[j]; }
        }
        __syncthreads();
        #pragma unroll
        for (int ks = 0; ks < 2; ks++) {
            bf16x8 ap = *(const bf16x8*)(&sc[mtw*16 + lm][kc + ks*32 + quad*8]);
            #pragma unroll
            for (int nt = 0; nt < 2; nt++) {
                int d = nhw*32 + nt*16 + lm;
                bf16x8 bv = *(const bf16x8*)(&kv[d][ks*32 + quad*8]);
                oc[nt] = mfma16(ap, bv, oc[nt]);
            }
        }
    }
    #pragma unroll
    for (int nt = 0; nt < 2; nt++)
    #pragma unroll
    for (int r = 0; r < 4; r++) {
        int row = mtw*16 + quad*4 + r;
        float val = oc[nt][r] * rinv[row];
        ctx[((size_t)(b*NS) + q0 + row) * ND + h*NHD + nhw*32 + nt*16 + lm] = (bf16_t)val;
    }
}

// -------------------- classifier head, stage 1: pr[b,n] = relu(x[b,0,:] @ preW + preb)
__global__ __launch_bounds__(256) void head_pre(const float* __restrict__ x,
                                                const void* __restrict__ preW,
                                                const void* __restrict__ preb,
                                                float* __restrict__ pr,
                                                const int* __restrict__ flagp) {
    const int isbf = flagp[0];
    int b = blockIdx.y;
    int n = blockIdx.x * 256 + threadIdx.x;
    const float* xr = x + (size_t)b * NS * ND;
    float s = loadf(preb, n, isbf);
    #pragma unroll 4
    for (int kk = 0; kk < ND; kk++) s += xr[kk] * loadf(preW, (size_t)kk * ND + n, isbf);
    pr[b * ND + n] = fmaxf(s, 0.f);
}

// -------------------- classifier head, stage 2: logits = pr @ clsW + clsb ----------
__global__ __launch_bounds__(256) void head_cls(const float* __restrict__ pr,
                                                const void* __restrict__ clsW,
                                                const void* __restrict__ clsb,
                                                void* __restrict__ out,
                                                const int* __restrict__ flagp) {
    const int isbf = flagp[0];
    int b = blockIdx.x, tid = threadIdx.x;
    __shared__ float red[256];
    for (int c = 0; c < 3; c++) {
        float s = 0.f;
        for (int kk = tid; kk < ND; kk += 256) s += pr[b * ND + kk] * loadf(clsW, kk * 3 + c, isbf);
        red[tid] = s;
        __syncthreads();
        for (int off = 128; off; off >>= 1) {
            if (tid < off) red[tid] += red[tid + off];
            __syncthreads();
        }
        if (tid == 0) {
            float v = red[0] + loadf(clsb, c, isbf);
            if (isbf) ((bf16_t*)out)[b * 3 + c] = (bf16_t)v;
            else      ((float*)out)[b * 3 + c] = v;
        }
        __syncthreads();
    }
}

extern "C" void kernel_launch(void* const* d_in, const int* in_sizes, int n_in,
                              void* d_out, int out_size, void* d_ws, size_t ws_size,
                              hipStream_t stream) {
    const int* ids   = (const int*)d_in[0];
    const int* segs  = (const int*)d_in[1];
    const int* mask  = (const int*)d_in[2];
    const void* emb  = d_in[4];
    const void* pos  = d_in[5];
    const void* elns = d_in[6];
    const void* elnb = d_in[7];
    const void* Wq = d_in[8];  const void* bq = d_in[9];
    const void* Wk = d_in[10]; const void* bk = d_in[11];
    const void* Wv = d_in[12]; const void* bv = d_in[13];
    const void* Wo = d_in[14]; const void* bo = d_in[15];
    const void* l1s = d_in[16]; const void* l1b = d_in[17];
    const void* W1 = d_in[18];  const void* b1 = d_in[19];
    const void* W2 = d_in[20];  const void* b2 = d_in[21];
    const void* l2s = d_in[22]; const void* l2b = d_in[23];
    const void* preW = d_in[24]; const void* preb = d_in[25];
    const void* clsW = d_in[26]; const void* clsb = d_in[27];

    // ---- workspace layout (deterministic function of ws_size) ----
    const size_t SZ_QKVB = NQKV * 2;                 // one of q/k/v/ctx, bf16
    size_t off = 0;
    auto alloc = [&](size_t sz) { size_t o = off; off = (off + sz + 255) & ~(size_t)255; return o; };
    size_t o_qkv  = alloc(3 * SZ_QKVB);              // q|k|v, also start of h1b alias
    size_t o_ctx  = alloc(SZ_QKVB);                  // h1b = [o_qkv .. o_ctx+SZ_QKVB) = 50.3MB
    size_t o_x    = alloc((size_t)NM * ND * 4);
    size_t o_xb   = alloc((size_t)NM * ND * 2);
    size_t o_pr   = alloc((size_t)NB * ND * 4);
    size_t o_flag = alloc(256);
    size_t o_w    = off;
    const size_t WQKV_L = (size_t)3 * ND * ND;       // per-layer fused qkv weight elems
    const size_t WSQ = (size_t)ND * ND, WF = (size_t)ND * NFF;
    size_t need_big = o_w + (NL * (WQKV_L + WSQ + 2 * WF)) * 2;
    int big = ws_size >= need_big;

    char* ws = (char*)d_ws;
    bf16_t* qkv  = (bf16_t*)(ws + o_qkv);
    bf16_t* ctxb = (bf16_t*)(ws + o_ctx);
    bf16_t* h1b  = (bf16_t*)(ws + o_qkv);
    float*  x    = (float*)(ws + o_x);
    bf16_t* xb   = (bf16_t*)(ws + o_xb);
    float*  pr   = (float*)(ws + o_pr);
    int*    flag = (int*)(ws + o_flag);
    size_t nlw = big ? NL : 1;
    bf16_t* wqkv = (bf16_t*)(ws + o_w);
    bf16_t* wo_t = wqkv + nlw * WQKV_L;
    bf16_t* w1_t = wo_t + nlw * WSQ;
    bf16_t* w2_t = w1_t + nlw * WF;

    detect_dtype<<<1, 64, 0, stream>>>(elns, flag);
    embed_ln<<<dim3(NS, NB), 256, 0, stream>>>(ids, segs, emb, pos, elns, elnb, x, xb, flag);

    dim3 tb(32, 8);
    if (big) {
        transpose_bt<<<dim3(24, 24, NL), tb, 0, stream>>>(Wq, 0, WSQ, wqkv,            WQKV_L, ND, ND, flag);
        transpose_bt<<<dim3(24, 24, NL), tb, 0, stream>>>(Wk, 0, WSQ, wqkv + WSQ,      WQKV_L, ND, ND, flag);
        transpose_bt<<<dim3(24, 24, NL), tb, 0, stream>>>(Wv, 0, WSQ, wqkv + 2 * WSQ,  WQKV_L, ND, ND, flag);
        transpose_bt<<<dim3(24, 24, NL), tb, 0, stream>>>(Wo, 0, WSQ, wo_t, WSQ, ND, ND, flag);
        transpose_bt<<<dim3(96, 24, NL), tb, 0, stream>>>(W1, 0, WF, w1_t, WF, ND, NFF, flag);
        transpose_bt<<<dim3(24, 96, NL), tb, 0, stream>>>(W2, 0, WF, w2_t, WF, NFF, ND, flag);
    }

    for (int l = 0; l < NL; l++) {
        if (!big) {
            transpose_bt<<<dim3(24, 24, 1), tb, 0, stream>>>(Wq, (size_t)l * WSQ, 0, wqkv,           0, ND, ND, flag);
            transpose_bt<<<dim3(24, 24, 1), tb, 0, stream>>>(Wk, (size_t)l * WSQ, 0, wqkv + WSQ,     0, ND, ND, flag);
            transpose_bt<<<dim3(24, 24, 1), tb, 0, stream>>>(Wv, (size_t)l * WSQ, 0, wqkv + 2 * WSQ, 0, ND, ND, flag);
            transpose_bt<<<dim3(24, 24, 1), tb, 0, stream>>>(Wo, (size_t)l * WSQ, 0, wo_t, 0, ND, ND, flag);
            transpose_bt<<<dim3(96, 24, 1), tb, 0, stream>>>(W1, (size_t)l * WF, 0, w1_t, 0, ND, NFF, flag);
            transpose_bt<<<dim3(24, 96, 1), tb, 0, stream>>>(W2, (size_t)l * WF, 0, w2_t, 0, NFF, ND, flag);
        }
        const bf16_t* wqkv_l = big ? wqkv + (size_t)l * WQKV_L : wqkv;
        const bf16_t* wo_l   = big ? wo_t + (size_t)l * WSQ : wo_t;
        const bf16_t* w1_l   = big ? w1_t + (size_t)l * WF : w1_t;
        const bf16_t* w2_l   = big ? w2_t + (size_t)l * WF : w2_t;

        gemm_bt<<<dim3(18, 64), 256, 0, stream>>>(xb, wqkv_l, bq, bk, bv, (size_t)l * ND, qkv, 2304, ND, 0, flag);
        attn<<<dim3(16, NH, NB), 256, 0, stream>>>(qkv, qkv + NQKV, qkv + 2 * NQKV, mask, ctxb);
        gemm_bt<<<dim3(6, 64), 256, 0, stream>>>(ctxb, wo_l, bo, nullptr, nullptr, (size_t)l * ND, x, ND, ND, 1, flag);
        ln_rows<<<NM, 256, 0, stream>>>(x, l1s, (size_t)l * ND, l1b, (size_t)l * ND, xb, flag);
        gemm_bt<<<dim3(24, 64), 256, 0, stream>>>(xb, w1_l, b1, nullptr, nullptr, (size_t)l * NFF, h1b, NFF, ND, 2, flag);
        gemm_bt<<<dim3(6, 64), 256, 0, stream>>>(h1b, w2_l, b2, nullptr, nullptr, (size_t)l * ND, x, ND, NFF, 1, flag);
        ln_rows<<<NM, 256, 0, stream>>>(x, l2s, (size_t)l * ND, l2b, (size_t)l * ND, xb, flag);
    }

    head_pre<<<dim3(3, NB), 256, 0, stream>>>(x, preW, preb, pr, flag);
    head_cls<<<NB, 256, 0, stream>>>(pr, clsW, clsb, d_out, flag);
}